// Round 7
// baseline (81.442 us; speedup 1.0000x reference)
//
#include <hip/hip_runtime.h>
#include <cstdint>
#include <cstddef>

typedef _Float16 f16x8 __attribute__((ext_vector_type(8)));
typedef _Float16 f16x2 __attribute__((ext_vector_type(2)));
typedef float    f32x16 __attribute__((ext_vector_type(16)));

#define MFMA32(a,b,c) __builtin_amdgcn_mfma_f32_32x32x16_f16((a),(b),(c),0,0,0)

// ws layout (halfs):
//  W1T  [15][64][256] @0        (245760)
//  W16T [64][368]     @245760   (23552)  sp: x col = 1808+sp; zero for sp<12
//  W2T  [4][64][256]  @269312   (65536)
//  W3T  [288][256]    @334848   (73728)  rows >= 260 zero
__global__ void tea_prep(const float* __restrict__ W1, const float* __restrict__ W16,
                         const float* __restrict__ W2, const float* __restrict__ W3,
                         _Float16* __restrict__ ws)
{
    int i = blockIdx.x * blockDim.x + threadIdx.x;
    if (i < 245760) {
        int k = i >> 14, r2 = i & 16383, o = r2 >> 8, s = r2 & 255;
        ws[i] = (_Float16)W1[((k << 8) | s) * 64 + o];
    } else if (i < 269312) {
        int r2 = i - 245760, o = r2 / 368, sp = r2 - o * 368;
        ws[i] = (_Float16)((sp >= 12) ? W16[(sp - 12) * 64 + o] : 0.f);
    } else if (i < 334848) {
        int r2 = i - 269312, g = r2 >> 14, rr = r2 & 16383, o = rr >> 8, s = rr & 255;
        ws[i] = (_Float16)W2[((g << 8) | s) * 64 + o];
    } else if (i < 408576) {
        int r2 = i - 334848, o = r2 >> 8, s = r2 & 255;
        ws[i] = (_Float16)((o < 260) ? W3[s * 260 + o] : 0.f);
    }
}

// One block = 32 batch rows, 4 independent waves (wave w = window group w).
// Swapped GEMMs throughout: D = W^T · x^T, so lane (l&31) = batch row everywhere.
// LDS 81920 B -> exactly 2 blocks/CU:
//   ylds[w] = sh + w*8192   [32][256] f16, XOR-swizzled, wave-private
//   zlds    = sh + 32768    [32][256] f16, XOR-swizzled, shared (1 barrier)
__global__ __launch_bounds__(256, 2)
void tea_main(const float* __restrict__ x,
              const float* __restrict__ b1,  const float* __restrict__ b16,
              const float* __restrict__ b2,  const float* __restrict__ b3,
              const _Float16* __restrict__ ws, float* __restrict__ out)
{
    __shared__ _Float16 sh[40960];
    const int tid = threadIdx.x, bid = blockIdx.x;
    const int w = tid >> 6, l = tid & 63;
    const int r = l & 31, h = l >> 5;
    _Float16* ylds = sh + w * 8192;
    _Float16* zlds = sh + 32768;
    const int swz = (r & 7) << 3;           // XOR on half-index, preserves 16B align

    const _Float16* wsW1  = ws;
    const _Float16* wsW16 = ws + 245760;
    const _Float16* wsW2  = ws + 269312;
    const _Float16* wsW3  = ws + 334848;

    const float* xl = x + (size_t)(bid * 32 + r) * 2176 + 8 * h;   // lane's row, its 8-col half

    float4 S[16];               // staging: one 128-col chunk (lane's 8 floats x 8 kk)
    f16x8 FA[8], FB[8], FC[8];  // three resident chunk frag-sets
    f32x16 acc0, acc1;

#define ZACC() do { _Pragma("unroll") for (int _i = 0; _i < 16; ++_i) { acc0[_i] = 0.f; acc1[_i] = 0.f; } } while (0)

    // stage chunk M (wave-local 0..4): 16 scattered float4 (cols 16kk+8h..+8 of lane row)
#define ISSUE(M) do { const float* _p = xl + (4 * w + (M)) * 128; \
    _Pragma("unroll") for (int _i = 0; _i < 8; ++_i) { \
        S[2*_i]   = *(const float4*)(_p + 16 * _i); \
        S[2*_i+1] = *(const float4*)(_p + 16 * _i + 4); } } while (0)

    // convert staged chunk to B-frags (RTN element casts, matches R1-R6 numerics)
#define CVT(F) do { _Pragma("unroll") for (int _i = 0; _i < 8; ++_i) { \
    f16x8 _f; float4 _u = S[2*_i], _v = S[2*_i+1]; \
    _f[0]=(_Float16)_u.x; _f[1]=(_Float16)_u.y; _f[2]=(_Float16)_u.z; _f[3]=(_Float16)_u.w; \
    _f[4]=(_Float16)_v.x; _f[5]=(_Float16)_v.y; _f[6]=(_Float16)_v.z; _f[7]=(_Float16)_v.w; \
    F[_i] = _f; } } while (0)

    // bias+relu+pack acc0/acc1 (C/D: col=r, row o=(m&3)+8*(m>>2)+4h) into swizzled LDS
#define STPACK(DST, KBASE, BIASP) do { \
    _Pragma("unroll") for (int _s = 0; _s < 2; ++_s) { \
      _Pragma("unroll") for (int _m = 0; _m < 8; ++_m) { \
        const int _o = 2 * (_m & 1) + 8 * (_m >> 1) + 4 * h + 32 * _s; \
        float _v0 = (_s ? acc1[2*_m]   : acc0[2*_m])   + (BIASP)[_o]; \
        float _v1 = (_s ? acc1[2*_m+1] : acc0[2*_m+1]) + (BIASP)[_o + 1]; \
        _v0 = _v0 > 0.f ? _v0 : 0.f; _v1 = _v1 > 0.f ? _v1 : 0.f; \
        f16x2 _hp; _hp[0] = (_Float16)_v0; _hp[1] = (_Float16)_v1; \
        *(f16x2*)&(DST)[(r * 256 + (KBASE) + _o) ^ swz] = _hp; } } } while (0)

    // window N (win = 4w+N, K=256): A=W1T rows (2 o-sets), B=chunk frags FL/FH
#define WINC(N, FL, FH) do { \
    const _Float16* _a = wsW1 + (4 * w + (N)) * 16384 + (size_t)r * 256 + 8 * h; \
    ZACC(); \
    _Pragma("unroll") for (int _kk = 0; _kk < 16; ++_kk) { \
        f16x8 _B = (_kk < 8) ? FL[_kk] : FH[_kk - 8]; \
        f16x8 _A0 = *(const f16x8*)(_a + 16 * _kk); \
        f16x8 _A1 = *(const f16x8*)(_a + 8192 + 16 * _kk); \
        acc0 = MFMA32(_A0, _B, acc0); \
        acc1 = MFMA32(_A1, _B, acc1); } \
    STPACK(ylds, (N) * 64, b1 + (4 * w + (N)) * 64); } while (0)

    // y16 (wave 3 only): K=368 re-based at col 1808; frags alias chunks 2,3,4 = FC,FA,FB
#define Y16C() do { \
    const _Float16* _a = wsW16 + (size_t)r * 368 + 8 * h; \
    ZACC(); \
    _Pragma("unroll") for (int _kk = 0; _kk < 23; ++_kk) { \
        f16x8 _B = (_kk < 7) ? FC[(_kk + 1) & 7] : ((_kk < 15) ? FA[(_kk + 1) & 7] : FB[(_kk + 1) & 7]); \
        f16x8 _A0 = *(const f16x8*)(_a + 16 * _kk); \
        f16x8 _A1 = *(const f16x8*)(_a + 32 * 368 + 16 * _kk); \
        acc0 = MFMA32(_A0, _B, acc0); \
        acc1 = MFMA32(_A1, _B, acc1); } \
    STPACK(ylds, 192, b16); } while (0)

    // ---- layer 1: 4 windows per wave, zero barriers, compiler-counted waits ----
    ISSUE(0); CVT(FA);
    ISSUE(1); CVT(FB);
    ISSUE(2);
    WINC(0, FA, FB);
    CVT(FC); ISSUE(3);
    WINC(1, FB, FC);
    CVT(FA); ISSUE(4);
    WINC(2, FC, FA);
    CVT(FB);
    if (w < 3) { WINC(3, FA, FB); } else { Y16C(); }

    // ---- layer 2 (wave-private): B = y frags from ylds, A = W2T[group w] ----
    f16x8 Zf[16];               // reused: first as y-frags, then as z-frags
    #pragma unroll
    for (int kk = 0; kk < 16; ++kk)
        Zf[kk] = *(const f16x8*)&ylds[(r * 256 + 16 * kk + 8 * h) ^ swz];
    {
        const _Float16* a2 = wsW2 + w * 16384 + (size_t)r * 256 + 8 * h;
        ZACC();
        #pragma unroll
        for (int kk = 0; kk < 16; ++kk) {
            f16x8 A0 = *(const f16x8*)(a2 + 16 * kk);
            f16x8 A1 = *(const f16x8*)(a2 + 8192 + 16 * kk);
            acc0 = MFMA32(A0, Zf[kk], acc0);
            acc1 = MFMA32(A1, Zf[kk], acc1);
        }
        STPACK(zlds, 64 * w, b2 + 64 * w);
    }
    __syncthreads();            // barrier 1: publish z (also proves all ylds reads done)

    // ---- layer 3: z frags shared; o-sets split across waves; pool into p[10] ----
    #pragma unroll
    for (int kk = 0; kk < 16; ++kk)
        Zf[kk] = *(const f16x8*)&zlds[(r * 256 + 16 * kk + 8 * h) ^ swz];

    float p[10];
    #pragma unroll
    for (int c = 0; c < 10; ++c) p[c] = 0.f;

#define L3S(S3) do { \
    const _Float16* _a3 = wsW3 + (size_t)(32 * (S3) + r) * 256 + 8 * h; \
    _Pragma("unroll") for (int _i = 0; _i < 16; ++_i) acc0[_i] = 0.f; \
    _Pragma("unroll") for (int _kk = 0; _kk < 16; ++_kk) { \
        f16x8 _A0 = *(const f16x8*)(_a3 + 16 * _kk); \
        acc0 = MFMA32(_A0, Zf[_kk], acc0); } \
    _Pragma("unroll") for (int _m = 0; _m < 16; ++_m) { \
        const int _o = 32 * (S3) + (_m & 3) + 8 * (_m >> 2); \
        int _ol = _o + 4 * h; \
        float _bb = (_ol < 260) ? b3[_ol] : 0.f; \
        float _v = acc0[_m] + _bb; _v = _v > 0.f ? _v : 0.f; \
        if (_o < 260)     p[_o / 26]       += (h == 0) ? _v : 0.f; \
        if (_o + 4 < 260) p[(_o + 4) / 26] += (h == 1) ? _v : 0.f; } } while (0)

    if      (w == 0) { L3S(0); L3S(4); L3S(8); }
    else if (w == 1) { L3S(1); L3S(5); }
    else if (w == 2) { L3S(2); L3S(6); }
    else             { L3S(3); L3S(7); }

    // ---- cross-wave/half pool reduce + softmax ----
    float* ps = (float*)sh;     // 8*32*10 f32 = 10240 B; ylds regions all dead post-barrier1
    {
        #pragma unroll
        for (int c = 0; c < 10; ++c)
            ps[((w * 2 + h) * 32 + r) * 10 + c] = p[c];
    }
    __syncthreads();            // barrier 2

    if (w == 0 && h == 0) {
        float q[10];
        #pragma unroll
        for (int c = 0; c < 10; ++c) {
            float s = 0.f;
            #pragma unroll
            for (int j = 0; j < 8; ++j) s += ps[(j * 32 + r) * 10 + c];
            q[c] = s;
        }
        float mx = q[0];
        #pragma unroll
        for (int c = 1; c < 10; ++c) mx = fmaxf(mx, q[c]);
        float e[10], se = 0.f;
        #pragma unroll
        for (int c = 0; c < 10; ++c) { e[c] = expf(q[c] - mx); se += e[c]; }
        float inv = 1.f / se;
        float* orow = out + (size_t)(bid * 32 + r) * 10;
        #pragma unroll
        for (int c = 0; c < 10; ++c) orow[c] = e[c] * inv;
    }

#undef ZACC
#undef ISSUE
#undef CVT
#undef STPACK
#undef WINC
#undef Y16C
#undef L3S
}

extern "C" void kernel_launch(void* const* d_in, const int* in_sizes, int n_in,
                              void* d_out, int out_size, void* d_ws, size_t ws_size,
                              hipStream_t stream)
{
    const float* x   = (const float*)d_in[0];
    const float* W1  = (const float*)d_in[1];
    const float* b1  = (const float*)d_in[2];
    const float* W16 = (const float*)d_in[3];
    const float* b16 = (const float*)d_in[4];
    const float* W2  = (const float*)d_in[5];
    const float* b2  = (const float*)d_in[6];
    const float* W3  = (const float*)d_in[7];
    const float* b3  = (const float*)d_in[8];
    float*    out = (float*)d_out;
    _Float16* ws  = (_Float16*)d_ws;

    tea_prep<<<1596, 256, 0, stream>>>(W1, W16, W2, W3, ws);
    tea_main<<<512, 256, 0, stream>>>(x, b1, b16, b2, b3, ws, out);
}

// Round 9
// 64.754 us; speedup vs baseline: 1.2577x; 1.2577x over previous
//
#include <hip/hip_runtime.h>
#include <cstdint>
#include <cstddef>

typedef _Float16 f16x8 __attribute__((ext_vector_type(8)));
typedef _Float16 f16x4 __attribute__((ext_vector_type(4)));
typedef float    f32x16 __attribute__((ext_vector_type(16)));

#define MFMA32(a,b,c) __builtin_amdgcn_mfma_f32_32x32x16_f16((a),(b),(c),0,0,0)

// ws layout (halfs) — ALL weights pre-swizzled into MFMA fragment-linear order:
//   W1F  [15][2][16][64][8] @0        (245760)   frag = win*16384 + side*8192 + kk*512 + l*8
//   W16F [2][23][64][8]     @245760   (23552)    x col = 1808+sp, zero sp<12  (sp=16kk+8h+j)
//   W2F  [4][2][16][64][8]  @269312   (65536)
//   W3F  [9][16][64][8]     @334848   (73728)    o-sets of 32; o>=260 zero
//   Y    [256][16384][4]    @408576   (16777216) o-block-transposed layer-1 output (ob = o>>2)
__global__ void tea_prep(const float* __restrict__ W1, const float* __restrict__ W16,
                         const float* __restrict__ W2, const float* __restrict__ W3,
                         _Float16* __restrict__ ws)
{
    int i = blockIdx.x * blockDim.x + threadIdx.x;
    if (i < 245760) {
        int win = i >> 14, t = i & 16383;
        int side = t >> 13, kk = (t >> 9) & 15, l = (t >> 3) & 63, j = t & 7;
        int o = 32 * side + (l & 31);
        int s = 16 * kk + 8 * (l >> 5) + j;
        ws[i] = (_Float16)W1[(win * 256 + s) * 64 + o];
    } else if (i < 269312) {
        int t = i - 245760;
        int side = t / 11776, t2 = t % 11776;
        int kk = t2 >> 9, l = (t2 >> 3) & 63, j = t2 & 7;
        int o = 32 * side + (l & 31);
        int sp = 16 * kk + 8 * (l >> 5) + j;
        ws[i] = (_Float16)((sp >= 12 && sp < 368) ? W16[(sp - 12) * 64 + o] : 0.f);
    } else if (i < 334848) {
        int t = i - 269312;
        int g = t >> 14, t2 = t & 16383;
        int side = t2 >> 13, kk = (t2 >> 9) & 15, l = (t2 >> 3) & 63, j = t2 & 7;
        int og = 32 * side + (l & 31);
        int s = 16 * kk + 8 * (l >> 5) + j;
        ws[i] = (_Float16)W2[(g * 256 + s) * 64 + og];
    } else if (i < 408576) {
        int t = i - 334848;
        int set = t >> 13;
        int kk = (t >> 9) & 15, l = (t >> 3) & 63, j = t & 7;
        int o = 32 * set + (l & 31);
        int s = 16 * kk + 8 * (l >> 5) + j;
        ws[i] = (_Float16)((o < 260) ? W3[s * 260 + o] : 0.f);
    }
}

// ---- layer 1 (+ y16 tail): block = (32-row tile, 4-window group), 2048 blocks ----
__global__ __launch_bounds__(256, 3)
void tea_l1(const float* __restrict__ x, const float* __restrict__ b1,
            const float* __restrict__ b16, const _Float16* __restrict__ ws,
            _Float16* __restrict__ y)
{
    __shared__ _Float16 xsm[32 * 648];
    const int bid = blockIdx.x;
    const int wg  = (bid & 7) * 256 + (bid >> 3);   // bijective XCD swizzle (2048%8==0)
    const int g = wg & 3, tile = wg >> 2;           // adjacent blocks share the row-tile
    const int tid = threadIdx.x;
    const int w = tid >> 6, l = tid & 63, r = l & 31, h = l >> 5;

    const float* xg = x + (size_t)(tile * 32) * 2176 + g * 512;

    // stage 32 rows x 640 cols: 20 coalesced float4 loads, then cvt+ds_write
    float4 S[20];
    #pragma unroll
    for (int c = 0; c < 5; ++c)
        #pragma unroll
        for (int it = 0; it < 4; ++it) {
            int e = it * 1024 + tid * 4;
            int row = e >> 7, col = e & 127;
            S[c * 4 + it] = *(const float4*)(xg + (size_t)row * 2176 + c * 128 + col);
        }
    #pragma unroll
    for (int c = 0; c < 5; ++c)
        #pragma unroll
        for (int it = 0; it < 4; ++it) {
            int e = it * 1024 + tid * 4;
            int row = e >> 7, col = e & 127;
            float4 u = S[c * 4 + it];
            f16x4 hv;
            hv[0] = (_Float16)u.x; hv[1] = (_Float16)u.y;
            hv[2] = (_Float16)u.z; hv[3] = (_Float16)u.w;
            *(f16x4*)&xsm[row * 648 + c * 128 + col] = hv;
        }
    __syncthreads();

    f32x16 acc0, acc1;
    #pragma unroll
    for (int i = 0; i < 16; ++i) { acc0[i] = 0.f; acc1[i] = 0.f; }

    auto store_y = [&](int obbase, const float* bp) {
        #pragma unroll
        for (int s = 0; s < 2; ++s)
            #pragma unroll
            for (int j = 0; j < 4; ++j) {
                int ol = 32 * s + 8 * j + 4 * h;
                f16x4 pk;
                #pragma unroll
                for (int t = 0; t < 4; ++t) {
                    float v = (s ? acc1[4 * j + t] : acc0[4 * j + t]) + bp[ol + t];
                    v = v > 0.f ? v : 0.f;
                    pk[t] = (_Float16)v;
                }
                *(f16x4*)(y + (size_t)(obbase + 8 * s + 2 * j + h) * 65536
                            + ((size_t)tile * 32 + r) * 4) = pk;
            }
    };

    if (g < 3 || w < 3) {
        const int win = 4 * g + w;
        const int cb  = 128 * w;                    // local col base in staged span
        const _Float16* A = ws + win * 16384;
        #pragma unroll
        for (int kk = 0; kk < 16; ++kk) {
            f16x8 B  = *(const f16x8*)&xsm[r * 648 + cb + 16 * kk + 8 * h];
            f16x8 A0 = *(const f16x8*)(A + kk * 512 + l * 8);
            f16x8 A1 = *(const f16x8*)(A + 8192 + kk * 512 + l * 8);
            acc0 = MFMA32(A0, B, acc0);
            acc1 = MFMA32(A1, B, acc1);
        }
        store_y(win * 16, b1 + win * 64);
    } else {
        // y16: K=368 at x col 1808 -> local col 272 in group-3 span [1536,2176)
        const _Float16* A = ws + 245760;
        #pragma unroll
        for (int kk = 0; kk < 23; ++kk) {
            f16x8 B  = *(const f16x8*)&xsm[r * 648 + 272 + 16 * kk + 8 * h];
            f16x8 A0 = *(const f16x8*)(A + kk * 512 + l * 8);
            f16x8 A1 = *(const f16x8*)(A + 11776 + kk * 512 + l * 8);
            acc0 = MFMA32(A0, B, acc0);
            acc1 = MFMA32(A1, B, acc1);
        }
        store_y(240, b16);
    }
}

// ---- layers 2+3 + pool + softmax: block = 32 rows, 512 blocks ----
__global__ __launch_bounds__(256, 2)
void tea_l2(const _Float16* __restrict__ y,
            const float* __restrict__ b2, const float* __restrict__ b3,
            const _Float16* __restrict__ ws, float* __restrict__ out)
{
    __shared__ _Float16 zsm[32 * 264];
    __shared__ float    ps[8 * 32 * 10];
    const int bid = blockIdx.x;
    const int wg  = (bid & 7) * 64 + (bid >> 3);    // bijective (512%8==0)
    const int tid = threadIdx.x;
    const int w = tid >> 6, l = tid & 63, r = l & 31, h = l >> 5;
    const size_t R = (size_t)wg * 32;
    const _Float16* W2F = ws + 269312;
    const _Float16* W3F = ws + 334848;
    const int swz = (r & 7) << 3;

    // layer 2: wave w -> z group w (o 64w..64w+63); B = y cols [256w,256w+256)
    f32x16 acc0, acc1;
    #pragma unroll
    for (int i = 0; i < 16; ++i) { acc0[i] = 0.f; acc1[i] = 0.f; }
    {
        const _Float16* A = W2F + w * 16384;
        #pragma unroll
        for (int kk = 0; kk < 16; ++kk) {
            int ob0 = 64 * w + 4 * kk + 2 * h;      // FIX: +64*w (wave's y column group)
            f16x4 lo = *(const f16x4*)(y + (size_t)ob0 * 65536 + (R + r) * 4);
            f16x4 hi = *(const f16x4*)(y + (size_t)(ob0 + 1) * 65536 + (R + r) * 4);
            f16x8 B;
            B[0] = lo[0]; B[1] = lo[1]; B[2] = lo[2]; B[3] = lo[3];
            B[4] = hi[0]; B[5] = hi[1]; B[6] = hi[2]; B[7] = hi[3];
            f16x8 A0 = *(const f16x8*)(A + kk * 512 + l * 8);
            f16x8 A1 = *(const f16x8*)(A + 8192 + kk * 512 + l * 8);
            acc0 = MFMA32(A0, B, acc0);
            acc1 = MFMA32(A1, B, acc1);
        }
        const float* bp = b2 + w * 64;
        #pragma unroll
        for (int s = 0; s < 2; ++s)
            #pragma unroll
            for (int j = 0; j < 4; ++j) {
                int ol = 64 * w + 32 * s + 8 * j + 4 * h;
                f16x4 pk;
                #pragma unroll
                for (int t = 0; t < 4; ++t) {
                    float v = (s ? acc1[4 * j + t] : acc0[4 * j + t]) + bp[32 * s + 8 * j + 4 * h + t];
                    v = v > 0.f ? v : 0.f;
                    pk[t] = (_Float16)v;
                }
                *(f16x4*)&zsm[r * 264 + (ol ^ swz)] = pk;
            }
    }
    __syncthreads();

    // layer 3: z frags from LDS; o-sets split across waves; pool per lane
    f16x8 Zf[16];
    #pragma unroll
    for (int kk = 0; kk < 16; ++kk)
        Zf[kk] = *(const f16x8*)&zsm[r * 264 + ((16 * kk + 8 * h) ^ swz)];

    float p[10];
    #pragma unroll
    for (int c = 0; c < 10; ++c) p[c] = 0.f;

    auto l3set = [&](int set) {
        const _Float16* A3 = W3F + set * 8192;
        f32x16 a;
        #pragma unroll
        for (int i = 0; i < 16; ++i) a[i] = 0.f;
        #pragma unroll
        for (int kk = 0; kk < 16; ++kk) {
            f16x8 A0 = *(const f16x8*)(A3 + kk * 512 + l * 8);
            a = MFMA32(A0, Zf[kk], a);
        }
        #pragma unroll
        for (int m = 0; m < 16; ++m) {
            int o = 32 * set + (m & 3) + 8 * (m >> 2) + 4 * h;
            if (o < 260) {
                float v = a[m] + b3[o];
                v = v > 0.f ? v : 0.f;
                p[(unsigned)o / 26u] += v;
            }
        }
    };
    if      (w == 0) { l3set(0); l3set(4); l3set(8); }
    else if (w == 1) { l3set(1); l3set(5); }
    else if (w == 2) { l3set(2); l3set(6); }
    else             { l3set(3); l3set(7); }

    #pragma unroll
    for (int c = 0; c < 10; ++c)
        ps[((w * 2 + h) * 32 + r) * 10 + c] = p[c];
    __syncthreads();

    if (w == 0 && h == 0) {
        float q[10];
        #pragma unroll
        for (int c = 0; c < 10; ++c) {
            float s = 0.f;
            #pragma unroll
            for (int j = 0; j < 8; ++j) s += ps[(j * 32 + r) * 10 + c];
            q[c] = s;
        }
        float mx = q[0];
        #pragma unroll
        for (int c = 1; c < 10; ++c) mx = fmaxf(mx, q[c]);
        float e[10], se = 0.f;
        #pragma unroll
        for (int c = 0; c < 10; ++c) { e[c] = expf(q[c] - mx); se += e[c]; }
        float inv = 1.f / se;
        float* orow = out + (R + r) * 10;
        #pragma unroll
        for (int c = 0; c < 10; ++c) orow[c] = e[c] * inv;
    }
}

extern "C" void kernel_launch(void* const* d_in, const int* in_sizes, int n_in,
                              void* d_out, int out_size, void* d_ws, size_t ws_size,
                              hipStream_t stream)
{
    const float* x   = (const float*)d_in[0];
    const float* W1  = (const float*)d_in[1];
    const float* b1  = (const float*)d_in[2];
    const float* W16 = (const float*)d_in[3];
    const float* b16 = (const float*)d_in[4];
    const float* W2  = (const float*)d_in[5];
    const float* b2  = (const float*)d_in[6];
    const float* W3  = (const float*)d_in[7];
    const float* b3  = (const float*)d_in[8];
    float*    out = (float*)d_out;
    _Float16* ws  = (_Float16*)d_ws;
    _Float16* y   = ws + 408576;

    tea_prep<<<1596, 256, 0, stream>>>(W1, W16, W2, W3, ws);
    tea_l1  <<<2048, 256, 0, stream>>>(x, b1, b16, ws, y);
    tea_l2  <<<512,  256, 0, stream>>>(y, b2, b3, ws, out);
}

// Round 10
// 64.335 us; speedup vs baseline: 1.2659x; 1.0065x over previous
//
#include <hip/hip_runtime.h>
#include <cstdint>
#include <cstddef>

typedef _Float16 f16x8 __attribute__((ext_vector_type(8)));
typedef _Float16 f16x4 __attribute__((ext_vector_type(4)));
typedef float    f32x16 __attribute__((ext_vector_type(16)));

#define MFMA32(a,b,c) __builtin_amdgcn_mfma_f32_32x32x16_f16((a),(b),(c),0,0,0)

// ws layout (halfs) — weights pre-swizzled into MFMA fragment-linear order:
//   W1F  [15][2][16][64][8] @0        (245760)   win*16384 + side*8192 + kk*512 + l*8
//   W16F [2][23][64][8]     @245760   (23552)    x col = 1808+sp, zero sp<12  (sp=16kk+8(l>>5)+j)
//   W2F  [4][2][16][64][8]  @269312   (65536)
//   W3F  [9][16][64][8]     @334848   (73728)    o-sets of 32; o>=260 zero
__global__ void tea_prep(const float* __restrict__ W1, const float* __restrict__ W16,
                         const float* __restrict__ W2, const float* __restrict__ W3,
                         _Float16* __restrict__ ws)
{
    int i = blockIdx.x * blockDim.x + threadIdx.x;
    if (i < 245760) {
        int win = i >> 14, t = i & 16383;
        int side = t >> 13, kk = (t >> 9) & 15, l = (t >> 3) & 63, j = t & 7;
        int o = 32 * side + (l & 31);
        int s = 16 * kk + 8 * (l >> 5) + j;
        ws[i] = (_Float16)W1[(win * 256 + s) * 64 + o];
    } else if (i < 269312) {
        int t = i - 245760;
        int side = t / 11776, t2 = t % 11776;
        int kk = t2 >> 9, l = (t2 >> 3) & 63, j = t2 & 7;
        int o = 32 * side + (l & 31);
        int sp = 16 * kk + 8 * (l >> 5) + j;
        ws[i] = (_Float16)((sp >= 12 && sp < 368) ? W16[(sp - 12) * 64 + o] : 0.f);
    } else if (i < 334848) {
        int t = i - 269312;
        int g = t >> 14, t2 = t & 16383;
        int side = t2 >> 13, kk = (t2 >> 9) & 15, l = (t2 >> 3) & 63, j = t2 & 7;
        int og = 32 * side + (l & 31);
        int s = 16 * kk + 8 * (l >> 5) + j;
        ws[i] = (_Float16)W2[(g * 256 + s) * 64 + og];
    } else if (i < 408576) {
        int t = i - 334848;
        int set = t >> 13;
        int kk = (t >> 9) & 15, l = (t >> 3) & 63, j = t & 7;
        int o = 32 * set + (l & 31);
        int s = 16 * kk + 8 * (l >> 5) + j;
        ws[i] = (_Float16)((o < 260) ? W3[s * 260 + o] : 0.f);
    }
}

// Fused: block = 32 batch rows, 1024 threads (16 waves), 1 block/CU.
// LDS map (halfs; sh[69888] = 139776 B):
//   xsm  stride 2184, [0, 69888)          x staged fp16 (dead after l1)
//   ylds stride 1032, [0, 33024)          aliases xsm (post-barrier 1)
//   zlds stride 264,  [33152, 41600)
//   ps   f32 18x32x10 @half 41600, [41600, 53120)
__global__ __launch_bounds__(1024, 4)
void tea_fused(const float* __restrict__ x,
               const float* __restrict__ b1,  const float* __restrict__ b16,
               const float* __restrict__ b2,  const float* __restrict__ b3,
               const _Float16* __restrict__ ws, float* __restrict__ out)
{
    __shared__ _Float16 sh[69888];
    _Float16* ylds = sh;
    _Float16* zlds = sh + 33152;
    float*    ps   = (float*)(sh + 41600);

    const int tid = threadIdx.x;
    const int bid = blockIdx.x;
    const int wg  = (bid & 7) * 64 + (bid >> 3);      // bijective XCD swizzle (512%8==0)
    const int q = tid >> 6, l = tid & 63, r = l & 31, h = l >> 5;

    const float* xg = x + (size_t)wg * 32 * 2176;

    // ---- stage x[32][2176] -> xsm fp16 (two register-bounded rounds) ----
    {
        float4 S[9];
        #pragma unroll
        for (int i = 0; i < 8; ++i) {
            int e = i * 4096 + tid * 4;
            S[i] = *(const float4*)(xg + (size_t)(e >> 11) * 2176 + (e & 2047));
        }
        #pragma unroll
        for (int i = 0; i < 8; ++i) {
            int e = i * 4096 + tid * 4;
            float4 u = S[i];
            f16x4 hv;
            hv[0] = (_Float16)u.x; hv[1] = (_Float16)u.y;
            hv[2] = (_Float16)u.z; hv[3] = (_Float16)u.w;
            *(f16x4*)&sh[(e >> 11) * 2184 + (e & 2047)] = hv;
        }
        #pragma unroll
        for (int i = 0; i < 8; ++i) {
            int e = (i + 8) * 4096 + tid * 4;
            S[i] = *(const float4*)(xg + (size_t)(e >> 11) * 2176 + (e & 2047));
        }
        S[8] = *(const float4*)(xg + (size_t)(tid >> 5) * 2176 + 2048 + (tid & 31) * 4);
        #pragma unroll
        for (int i = 0; i < 8; ++i) {
            int e = (i + 8) * 4096 + tid * 4;
            float4 u = S[i];
            f16x4 hv;
            hv[0] = (_Float16)u.x; hv[1] = (_Float16)u.y;
            hv[2] = (_Float16)u.z; hv[3] = (_Float16)u.w;
            *(f16x4*)&sh[(e >> 11) * 2184 + (e & 2047)] = hv;
        }
        {
            float4 u = S[8];
            f16x4 hv;
            hv[0] = (_Float16)u.x; hv[1] = (_Float16)u.y;
            hv[2] = (_Float16)u.z; hv[3] = (_Float16)u.w;
            *(f16x4*)&sh[(tid >> 5) * 2184 + 2048 + (tid & 31) * 4] = hv;
        }
    }
    __syncthreads();                                   // barrier 0: x staged

    // ---- layer 1: wave q -> window q (q<15) or y16 tail (q==15) ----
    f32x16 acc0, acc1;
    #pragma unroll
    for (int i = 0; i < 16; ++i) { acc0[i] = 0.f; acc1[i] = 0.f; }

    if (q < 15) {
        const _Float16* A = ws + q * 16384;
        const int cb = 128 * q;
        #pragma unroll
        for (int kk = 0; kk < 16; ++kk) {
            f16x8 B  = *(const f16x8*)&sh[r * 2184 + cb + 16 * kk + 8 * h];
            f16x8 A0 = *(const f16x8*)(A + kk * 512 + l * 8);
            f16x8 A1 = *(const f16x8*)(A + 8192 + kk * 512 + l * 8);
            acc0 = MFMA32(A0, B, acc0);
            acc1 = MFMA32(A1, B, acc1);
        }
    } else {
        const _Float16* A = ws + 245760;
        #pragma unroll
        for (int kk = 0; kk < 23; ++kk) {
            f16x8 B  = *(const f16x8*)&sh[r * 2184 + 1808 + 16 * kk + 8 * h];
            f16x8 A0 = *(const f16x8*)(A + kk * 512 + l * 8);
            f16x8 A1 = *(const f16x8*)(A + 11776 + kk * 512 + l * 8);
            acc0 = MFMA32(A0, B, acc0);
            acc1 = MFMA32(A1, B, acc1);
        }
    }
    __syncthreads();                                   // barrier 1: all xsm reads done

    // ---- y -> ylds (bias+relu+pack); wave q owns y cols [64q, 64q+64) ----
    {
        const float* bp = (q < 15) ? (b1 + q * 64) : b16;
        #pragma unroll
        for (int s = 0; s < 2; ++s)
            #pragma unroll
            for (int j = 0; j < 4; ++j) {
                f16x4 pk;
                #pragma unroll
                for (int t = 0; t < 4; ++t) {
                    float v = (s ? acc1[4 * j + t] : acc0[4 * j + t]) + bp[32 * s + 8 * j + 4 * h + t];
                    v = v > 0.f ? v : 0.f;
                    pk[t] = (_Float16)v;
                }
                *(f16x4*)&ylds[r * 1032 + q * 64 + 32 * s + 8 * j + 4 * h] = pk;
            }
    }
    __syncthreads();                                   // barrier 2: y published

    // ---- layer 2: waves 0..7 -> (group g = q>>1, side = q&1), 32 z-outs each ----
    if (q < 8) {
        const int g = q >> 1, sd = q & 1;
        const _Float16* A = ws + 269312 + g * 16384 + sd * 8192;
        f32x16 a;
        #pragma unroll
        for (int i = 0; i < 16; ++i) a[i] = 0.f;
        #pragma unroll
        for (int kk = 0; kk < 16; ++kk) {
            f16x8 B  = *(const f16x8*)&ylds[r * 1032 + 256 * g + 16 * kk + 8 * h];
            f16x8 A0 = *(const f16x8*)(A + kk * 512 + l * 8);
            a = MFMA32(A0, B, a);
        }
        const float* bz = b2 + g * 64 + 32 * sd;
        #pragma unroll
        for (int j = 0; j < 4; ++j) {
            f16x4 pk;
            #pragma unroll
            for (int t = 0; t < 4; ++t) {
                float v = a[4 * j + t] + bz[8 * j + 4 * h + t];
                v = v > 0.f ? v : 0.f;
                pk[t] = (_Float16)v;
            }
            *(f16x4*)&zlds[r * 264 + g * 64 + sd * 32 + 8 * j + 4 * h] = pk;
        }
    }
    __syncthreads();                                   // barrier 3: z published

    // ---- layer 3: waves 0..8 -> o-set q; pool per lane; partials to ps ----
    if (q < 9) {
        const _Float16* A3 = ws + 334848 + q * 8192;
        f32x16 a;
        #pragma unroll
        for (int i = 0; i < 16; ++i) a[i] = 0.f;
        #pragma unroll
        for (int kk = 0; kk < 16; ++kk) {
            f16x8 B  = *(const f16x8*)&zlds[r * 264 + 16 * kk + 8 * h];
            f16x8 A0 = *(const f16x8*)(A3 + kk * 512 + l * 8);
            a = MFMA32(A0, B, a);
        }
        float p[10];
        #pragma unroll
        for (int c = 0; c < 10; ++c) p[c] = 0.f;
        #pragma unroll
        for (int m = 0; m < 16; ++m) {
            int o = 32 * q + (m & 3) + 8 * (m >> 2) + 4 * h;
            if (o < 260) {
                float v = a[m] + b3[o];
                v = v > 0.f ? v : 0.f;
                p[(unsigned)o / 26u] += v;
            }
        }
        #pragma unroll
        for (int c = 0; c < 10; ++c)
            ps[(q * 2 + h) * 320 + r * 10 + c] = p[c];
    }
    __syncthreads();                                   // barrier 4: partials in

    // ---- reduce 18 partial groups + softmax; lanes 0..31 of wave 0 ----
    if (tid < 32) {
        float v[10];
        #pragma unroll
        for (int c = 0; c < 10; ++c) {
            float s = 0.f;
            #pragma unroll
            for (int j = 0; j < 18; ++j) s += ps[j * 320 + tid * 10 + c];
            v[c] = s;
        }
        float mx = v[0];
        #pragma unroll
        for (int c = 1; c < 10; ++c) mx = fmaxf(mx, v[c]);
        float e[10], se = 0.f;
        #pragma unroll
        for (int c = 0; c < 10; ++c) { e[c] = expf(v[c] - mx); se += e[c]; }
        float inv = 1.f / se;
        float* orow = out + (size_t)(wg * 32 + tid) * 10;
        #pragma unroll
        for (int c = 0; c < 10; ++c) orow[c] = e[c] * inv;
    }
}

extern "C" void kernel_launch(void* const* d_in, const int* in_sizes, int n_in,
                              void* d_out, int out_size, void* d_ws, size_t ws_size,
                              hipStream_t stream)
{
    const float* x   = (const float*)d_in[0];
    const float* W1  = (const float*)d_in[1];
    const float* b1  = (const float*)d_in[2];
    const float* W16 = (const float*)d_in[3];
    const float* b16 = (const float*)d_in[4];
    const float* W2  = (const float*)d_in[5];
    const float* b2  = (const float*)d_in[6];
    const float* W3  = (const float*)d_in[7];
    const float* b3  = (const float*)d_in[8];
    float*    out = (float*)d_out;
    _Float16* ws  = (_Float16*)d_ws;

    tea_prep <<<1596, 256, 0, stream>>>(W1, W16, W2, W3, ws);
    tea_fused<<<512, 1024, 0, stream>>>(x, b1, b16, b2, b3, ws, out);
}